// Round 1
// baseline (12419.704 us; speedup 1.0000x reference)
//
#include <hip/hip_runtime.h>

#define N_CLOUDS 16
#define PTS      16384
#define M        4096
#define THREADS  1024
#define PPT      (PTS / THREADS)   // 16 points per thread
#define NWAVES   (THREADS / 64)    // 16 waves

// One block per cloud. FPS: start at point 0, iteratively pick argmax of
// min-distance-to-selected-set. Matches jnp reference semantics:
//  - argmax takes FIRST occurrence of the max (tie-break: smaller index)
//  - distances computed as ((x-qx)^2 + (y-qy)^2) + (z-qz)^2 in fp32,
//    NO fma contraction (explicit __fmul_rn/__fadd_rn) to match numpy rounding.
__global__ __launch_bounds__(THREADS, 1) void fps_kernel(
    const float* __restrict__ pos, int* __restrict__ out)
{
    const int cloud = blockIdx.x;
    const int tid   = threadIdx.x;
    const int base  = cloud * PTS;      // global index of first point in cloud

    __shared__ float sd[NWAVES];
    __shared__ int   si[NWAVES];

    // ---- load my 16 points into registers; init dist to point 0 of cloud ----
    const float q0x = pos[base * 3 + 0];
    const float q0y = pos[base * 3 + 1];
    const float q0z = pos[base * 3 + 2];

    float px[PPT], py[PPT], pz[PPT], d[PPT];
#pragma unroll
    for (int k = 0; k < PPT; ++k) {
        const int li  = tid + k * THREADS;       // local point index in cloud
        const int off = (base + li) * 3;
        px[k] = pos[off + 0];
        py[k] = pos[off + 1];
        pz[k] = pos[off + 2];
        const float dx = __fsub_rn(px[k], q0x);
        const float dy = __fsub_rn(py[k], q0y);
        const float dz = __fsub_rn(pz[k], q0z);
        d[k] = __fadd_rn(__fadd_rn(__fmul_rn(dx, dx), __fmul_rn(dy, dy)),
                         __fmul_rn(dz, dz));
    }

    if (tid == 0) out[cloud * M] = base;   // first sample is point 0

    const int wave = tid >> 6;
    const int lane = tid & 63;

    for (int i = 1; i < M; ++i) {
        // ---- lane-local argmax over my 16 dists (strict > keeps smallest li) ----
        float bd = d[0];
        int   bi = tid;                     // li for k==0 is tid
#pragma unroll
        for (int k = 1; k < PPT; ++k) {
            const int li = tid + k * THREADS;
            if (d[k] > bd) { bd = d[k]; bi = li; }
        }

        // ---- wave-level shuffle reduce (64 lanes), tie-break smaller idx ----
#pragma unroll
        for (int off = 32; off >= 1; off >>= 1) {
            const float od = __shfl_down(bd, off);
            const int   oi = __shfl_down(bi, off);
            if (od > bd || (od == bd && oi < bi)) { bd = od; bi = oi; }
        }

        if (lane == 0) { sd[wave] = bd; si[wave] = bi; }
        __syncthreads();

        // ---- every thread reduces the 16 wave winners (deterministic) ----
        float wd = sd[0];
        int   wi = si[0];
#pragma unroll
        for (int j = 1; j < NWAVES; ++j) {
            const float od = sd[j];
            const int   oi = si[j];
            if (od > wd || (od == wd && oi < wi)) { wd = od; wi = oi; }
        }
        __syncthreads();   // protect LDS before next iteration's leader writes

        if (tid == 0) out[cloud * M + i] = base + wi;

        // ---- fetch winner coords (uniform address -> scalarize) ----
        const int wiu  = __builtin_amdgcn_readfirstlane(wi);
        const int qoff = (base + wiu) * 3;
        const float qx = pos[qoff + 0];
        const float qy = pos[qoff + 1];
        const float qz = pos[qoff + 2];

        // ---- fused distance update (exact rounding: no fma contraction) ----
#pragma unroll
        for (int k = 0; k < PPT; ++k) {
            const float dx = __fsub_rn(px[k], qx);
            const float dy = __fsub_rn(py[k], qy);
            const float dz = __fsub_rn(pz[k], qz);
            const float nd = __fadd_rn(__fadd_rn(__fmul_rn(dx, dx),
                                                 __fmul_rn(dy, dy)),
                                       __fmul_rn(dz, dz));
            d[k] = fminf(d[k], nd);
        }
    }
}

extern "C" void kernel_launch(void* const* d_in, const int* in_sizes, int n_in,
                              void* d_out, int out_size, void* d_ws, size_t ws_size,
                              hipStream_t stream) {
    const float* pos = (const float*)d_in[0];
    int* out = (int*)d_out;
    fps_kernel<<<N_CLOUDS, THREADS, 0, stream>>>(pos, out);
}

// Round 2
// 7012.707 us; speedup vs baseline: 1.7710x; 1.7710x over previous
//
#include <hip/hip_runtime.h>

#define N_CLOUDS 16
#define PTS      16384
#define M        4096
#define THREADS  512
#define PPT      (PTS / THREADS)   // 32 points per thread
#define PPT2     (PPT / 2)         // 16 v2f pairs per thread
#define NWAVES   (THREADS / 64)    // 8 waves

typedef float v2f __attribute__((ext_vector_type(2)));
typedef unsigned long long u64;
typedef unsigned int u32;

// One block per cloud; serial FPS, latency-optimized:
//  - update + lane-local argmax fused (one pass over the 32 pts/thread)
//  - u64 key = (f32 dist bits << 32) | ~local_idx  -> max() does argmax with
//    first-occurrence (smallest index) tie-break, branch-free
//  - ONE __syncthreads per iteration (parity double-buffered wave-winner LDS)
//  - packed fp32 (v2f) arithmetic, fp contract off for numpy-exact rounding
__global__ __launch_bounds__(THREADS, 2) void fps_kernel(
    const float* __restrict__ pos, int* __restrict__ out)
{
#pragma clang fp contract(off)
    const int cloud = blockIdx.x;
    const int tid   = threadIdx.x;
    const int base  = cloud * PTS;

    __shared__ u64 skey[2][NWAVES];

    // ---- load my 32 points (pairs) and init dist to point 0 of cloud ----
    const float q0x = pos[(size_t)base * 3 + 0];
    const float q0y = pos[(size_t)base * 3 + 1];
    const float q0z = pos[(size_t)base * 3 + 2];
    v2f qx2 = {q0x, q0x}, qy2 = {q0y, q0y}, qz2 = {q0z, q0z};

    v2f px[PPT2], py[PPT2], pz[PPT2], d[PPT2];
    float bd = -1.0f;   // running lane-local argmax (dists are >= 0)
    int   bk = 0;       // slot (0..31); li = tid + bk*THREADS
#pragma unroll
    for (int j = 0; j < PPT2; ++j) {
        const int li0 = tid + (2 * j) * THREADS;
        const int li1 = li0 + THREADS;
        const size_t o0 = (size_t)(base + li0) * 3;
        const size_t o1 = (size_t)(base + li1) * 3;
        px[j] = (v2f){pos[o0 + 0], pos[o1 + 0]};
        py[j] = (v2f){pos[o0 + 1], pos[o1 + 1]};
        pz[j] = (v2f){pos[o0 + 2], pos[o1 + 2]};
        v2f dx = px[j] - qx2;
        v2f dy = py[j] - qy2;
        v2f dz = pz[j] - qz2;
        v2f nd = dx * dx + dy * dy + dz * dz;   // ((x^2+y^2)+z^2), no fma
        d[j] = nd;
        if (nd.x > bd) { bd = nd.x; bk = 2 * j; }
        if (nd.y > bd) { bd = nd.y; bk = 2 * j + 1; }
    }

    if (tid == 0) out[cloud * M] = base;   // first sample = point 0

    const int wave = tid >> 6;
    const int lane = tid & 63;

    for (int i = 1; i < M; ++i) {
        // ---- build u64 key: high = dist bits (>=0 so monotone), low = ~li ----
        const int bi = tid + bk * THREADS;
        u64 key = ((u64)__float_as_uint(bd) << 32) | (u32)(~bi);

        // ---- wave-level max-reduce (argmax with smallest-index tie-break) ----
#pragma unroll
        for (int off = 32; off >= 1; off >>= 1) {
            const u64 ok = __shfl_down(key, off);
            key = (ok > key) ? ok : key;
        }
        if (lane == 0) skey[i & 1][wave] = key;
        __syncthreads();

        // ---- every thread reduces the 8 wave winners (deterministic) ----
        u64 wk = skey[i & 1][0];
#pragma unroll
        for (int j = 1; j < NWAVES; ++j) {
            const u64 ok = skey[i & 1][j];
            wk = (ok > wk) ? ok : wk;
        }
        const int wi = (int)(~(u32)wk);        // local index of winner
        if (tid == 0) out[cloud * M + i] = base + wi;

        // ---- fetch winner coords (uniform -> scalar loads) ----
        const int wiu = __builtin_amdgcn_readfirstlane(wi);
        const float* qp = pos + (size_t)(base + wiu) * 3;
        const float qx = qp[0], qy = qp[1], qz = qp[2];
        qx2 = (v2f){qx, qx}; qy2 = (v2f){qy, qy}; qz2 = (v2f){qz, qz};

        // ---- fused distance update + lane-local argmax of the NEW dists ----
        bd = -1.0f; bk = 0;
#pragma unroll
        for (int j = 0; j < PPT2; ++j) {
            v2f dx = px[j] - qx2;
            v2f dy = py[j] - qy2;
            v2f dz = pz[j] - qz2;
            v2f nd = dx * dx + dy * dy + dz * dz;   // no fma (contract off)
            v2f nm;
            nm.x = fminf(d[j].x, nd.x);
            nm.y = fminf(d[j].y, nd.y);
            d[j] = nm;
            if (nm.x > bd) { bd = nm.x; bk = 2 * j; }
            if (nm.y > bd) { bd = nm.y; bk = 2 * j + 1; }
        }
    }
}

extern "C" void kernel_launch(void* const* d_in, const int* in_sizes, int n_in,
                              void* d_out, int out_size, void* d_ws, size_t ws_size,
                              hipStream_t stream) {
    const float* pos = (const float*)d_in[0];
    int* out = (int*)d_out;
    fps_kernel<<<N_CLOUDS, THREADS, 0, stream>>>(pos, out);
}

// Round 3
// 6757.369 us; speedup vs baseline: 1.8379x; 1.0378x over previous
//
#include <hip/hip_runtime.h>

#define N_CLOUDS 16
#define PTS      16384
#define M        4096
#define THREADS  512
#define NWAVES   (THREADS / 64)    // 8 waves

typedef float v2f __attribute__((ext_vector_type(2)));
typedef unsigned long long u64;
typedef unsigned int u32;

// One block per cloud; serial FPS, latency-optimized.
// Round-3 change: point/dist storage as EXPLICIT scalar v2f variables (macro
// expanded) — round 2's v2f arrays were demoted to scratch (VGPR_Count=80 <
// 128 needed), costing ~2500 cyc/iter of L2 scratch traffic. No arrays, no
// dynamic indexing => guaranteed register residency (~150 VGPRs < 256 cap).
//  - u64 key = (f32 dist bits << 32) | ~local_idx -> branch-free argmax with
//    first-occurrence (smallest index) tie-break, matching jnp.argmax
//  - ONE __syncthreads per iteration (parity double-buffered wave-winner LDS)
//  - fp contract off => bit-exact vs numpy reference (round 2: absmax = 0)

#define GROUPS_X(X) X(0) X(1) X(2) X(3) X(4) X(5) X(6) X(7) \
                    X(8) X(9) X(10) X(11) X(12) X(13) X(14) X(15)

__global__ __launch_bounds__(THREADS, 2) void fps_kernel(
    const float* __restrict__ pos, int* __restrict__ out)
{
#pragma clang fp contract(off)
    const int cloud = blockIdx.x;
    const int tid   = threadIdx.x;
    const int base  = cloud * PTS;

    __shared__ u64 skey[2][NWAVES];

    // ---- query = point 0 of cloud ----
    const float q0x = pos[(size_t)base * 3 + 0];
    const float q0y = pos[(size_t)base * 3 + 1];
    const float q0z = pos[(size_t)base * 3 + 2];
    v2f qx2 = {q0x, q0x}, qy2 = {q0y, q0y}, qz2 = {q0z, q0z};

    // ---- explicit register storage: 16 v2f per coord (slots 2j, 2j+1) ----
#define DECL(j) v2f px##j, py##j, pz##j, d##j;
    GROUPS_X(DECL)
#undef DECL

    float bd = -1.0f;   // lane-local running max of min-dists
    int   bk = 0;       // slot 0..31; li = tid + bk*THREADS

#define INIT(j) { \
        const int li0 = tid + (2*(j)) * THREADS; \
        const size_t o0 = (size_t)(base + li0) * 3; \
        const size_t o1 = o0 + (size_t)THREADS * 3; \
        px##j = (v2f){pos[o0 + 0], pos[o1 + 0]}; \
        py##j = (v2f){pos[o0 + 1], pos[o1 + 1]}; \
        pz##j = (v2f){pos[o0 + 2], pos[o1 + 2]}; \
        v2f dx = px##j - qx2; \
        v2f dy = py##j - qy2; \
        v2f dz = pz##j - qz2; \
        v2f nd = dx * dx + dy * dy + dz * dz; \
        d##j = nd; \
        if (nd.x > bd) { bd = nd.x; bk = 2*(j); } \
        if (nd.y > bd) { bd = nd.y; bk = 2*(j) + 1; } \
    }
    GROUPS_X(INIT)
#undef INIT

    if (tid == 0) out[cloud * M] = base;   // first sample = point 0

    const int wave = tid >> 6;
    const int lane = tid & 63;

    for (int i = 1; i < M; ++i) {
        // ---- u64 key: high = dist bits (>=0 so uint-monotone), low = ~li ----
        const int bi = tid + bk * THREADS;
        u64 key = ((u64)__float_as_uint(bd) << 32) | (u32)(~bi);

        // ---- wave-level max-reduce (argmax, smallest-index tie-break) ----
#pragma unroll
        for (int off = 32; off >= 1; off >>= 1) {
            const u64 ok = __shfl_down(key, off);
            key = (ok > key) ? ok : key;
        }
        if (lane == 0) skey[i & 1][wave] = key;
        __syncthreads();

        // ---- every thread reduces the 8 wave winners (deterministic) ----
        u64 wk = skey[i & 1][0];
#pragma unroll
        for (int j = 1; j < NWAVES; ++j) {
            const u64 ok = skey[i & 1][j];
            wk = (ok > wk) ? ok : wk;
        }
        const int wi = (int)(~(u32)wk);        // winner local index
        if (tid == 0) out[cloud * M + i] = base + wi;

        // ---- fetch winner coords (uniform address -> scalar load) ----
        const int wiu = __builtin_amdgcn_readfirstlane(wi);
        const float* qp = pos + (size_t)(base + wiu) * 3;
        const float qx = qp[0], qy = qp[1], qz = qp[2];
        qx2 = (v2f){qx, qx}; qy2 = (v2f){qy, qy}; qz2 = (v2f){qz, qz};

        // ---- fused distance update + lane-local argmax (ascending slots) ----
        bd = -1.0f; bk = 0;
#define UPD(j) { \
        v2f dx = px##j - qx2; \
        v2f dy = py##j - qy2; \
        v2f dz = pz##j - qz2; \
        v2f nd = dx * dx + dy * dy + dz * dz; \
        d##j.x = fminf(d##j.x, nd.x); \
        d##j.y = fminf(d##j.y, nd.y); \
        if (d##j.x > bd) { bd = d##j.x; bk = 2*(j); } \
        if (d##j.y > bd) { bd = d##j.y; bk = 2*(j) + 1; } \
    }
        GROUPS_X(UPD)
#undef UPD
    }
}

extern "C" void kernel_launch(void* const* d_in, const int* in_sizes, int n_in,
                              void* d_out, int out_size, void* d_ws, size_t ws_size,
                              hipStream_t stream) {
    const float* pos = (const float*)d_in[0];
    int* out = (int*)d_out;
    fps_kernel<<<N_CLOUDS, THREADS, 0, stream>>>(pos, out);
}